// Round 4
// baseline (28.192 us; speedup 1.0000x reference)
//
#include <hip/hip_runtime.h>
#include <math.h>

#define NI 6
#define NC 10
#define C_IN 512
#define N_POS 4096
#define B_SZ 2

// ws layout (floats):
//   ctx     @ 0       [8192][6]
//   q       @ 49152   [8192][6]
//   k       @ 98304
//   v       @ 147456
//   qd      @ 196608
//   kd      @ 245760
//   partial @ 294912  [10][256]
//   counter @ 297472  (int)

// ---------------------------------------------------------------------------
// k_fused: context = relu(Wc@features+bc) -> out = Wo@context+bo + logits
// partials. ctx always written; Q/K/V/QD/KD iff beta != 0 (out/partials are
// then speculative; k_attn overwrites them). Block 0 zeroes the completion
// counter used by k_attn's last-block logits finalize.
// Grid: 256 blocks x 256 thr. Block = 32 consecutive positions, 512 channels.
// Thread: quad q = t&7 (one float4 = 4 positions), ch = t>>3 (16 channels,
// c = cc*32+ch). All 16 feature loads are issued up-front so HBM latency
// hides under the Wc staging + barrier.
// ---------------------------------------------------------------------------
__global__ __launch_bounds__(256) void k_fused(
    const float* __restrict__ feat, const float* __restrict__ cam,
    const float* __restrict__ Wc,  const float* __restrict__ bc,
    const float* __restrict__ Wq,  const float* __restrict__ bq,
    const float* __restrict__ Wk,  const float* __restrict__ bk,
    const float* __restrict__ Wv,  const float* __restrict__ bv,
    const float* __restrict__ Wcq, const float* __restrict__ bcq,
    const float* __restrict__ Wck, const float* __restrict__ bck,
    const float* __restrict__ Wo,  const float* __restrict__ bo,
    const float* __restrict__ beta,
    float* __restrict__ ctx, float* __restrict__ qb, float* __restrict__ kb,
    float* __restrict__ vb, float* __restrict__ qdb, float* __restrict__ kdb,
    float* __restrict__ partial, float* __restrict__ out, int* __restrict__ counter)
{
    __shared__ float sW[C_IN * 8];        // [c][8] pad; d<6 valid
    __shared__ float sPart[32 * 8 * 25];  // [ch][q][24 + 1 pad] (25 coprime 32)
    __shared__ float sE[32 * NI];         // relu'd context, [pos][d]

    const int t   = threadIdx.x;
    const int bid = blockIdx.x;
    const int b   = bid >> 7;             // 128 blocks per batch
    const int n0  = (bid & 127) * 32;

    const int q  = t & 7;                 // position quad: n0 + q*4 .. +3
    const int ch = t >> 3;                // 0..31
    const float* f = feat + (size_t)b * C_IN * N_POS + n0 + q * 4;

    // issue Wc staging loads first (oldest), then all 16 feature loads;
    // the sW ds_writes then only wait for the staging loads while the
    // feature loads keep streaming.
    float wreg[12];
    #pragma unroll
    for (int i0 = 0; i0 < 12; ++i0) wreg[i0] = Wc[t + i0 * 256];

    float4 x[16];
    #pragma unroll
    for (int cc = 0; cc < 16; ++cc)
        x[cc] = *(const float4*)(f + (size_t)(cc * 32 + ch) * N_POS);

    if (bid == 0 && t == 0) *counter = 0;   // reset for k_attn's finalize

    #pragma unroll
    for (int i0 = 0; i0 < 12; ++i0) {
        const int i = t + i0 * 256;         // i = d*512 + c
        sW[(i & 511) * 8 + (i >> 9)] = wreg[i0];
    }
    __syncthreads();

    float acc[24];                        // acc[po*6+d]
    #pragma unroll
    for (int i = 0; i < 24; ++i) acc[i] = 0.f;

    #pragma unroll
    for (int cc = 0; cc < 16; ++cc) {
        const int c = cc * 32 + ch;
        const float4 xx = x[cc];
        const float4 w0 = *(const float4*)(&sW[c * 8]);
        const float2 w1 = *(const float2*)(&sW[c * 8 + 4]);
        acc[0]  += w0.x * xx.x; acc[6]  += w0.x * xx.y; acc[12] += w0.x * xx.z; acc[18] += w0.x * xx.w;
        acc[1]  += w0.y * xx.x; acc[7]  += w0.y * xx.y; acc[13] += w0.y * xx.z; acc[19] += w0.y * xx.w;
        acc[2]  += w0.z * xx.x; acc[8]  += w0.z * xx.y; acc[14] += w0.z * xx.z; acc[20] += w0.z * xx.w;
        acc[3]  += w0.w * xx.x; acc[9]  += w0.w * xx.y; acc[15] += w0.w * xx.z; acc[21] += w0.w * xx.w;
        acc[4]  += w1.x * xx.x; acc[10] += w1.x * xx.y; acc[16] += w1.x * xx.z; acc[22] += w1.x * xx.w;
        acc[5]  += w1.y * xx.x; acc[11] += w1.y * xx.y; acc[17] += w1.y * xx.z; acc[23] += w1.y * xx.w;
    }

    {
        float* sp = &sPart[(ch * 8 + q) * 25];
        #pragma unroll
        for (int j = 0; j < 24; ++j) sp[j] = acc[j];
    }
    __syncthreads();

    // reduce over the 32 channel-chunks: 192 threads, one (pos,d) each
    if (t < 192) {
        const int pos = t / 6, d = t - pos * 6;   // t == pos*6+d
        const int qq = pos >> 2, po = pos & 3;
        float s = bc[d];
        #pragma unroll
        for (int c2 = 0; c2 < 32; ++c2)
            s += sPart[(c2 * 8 + qq) * 25 + po * 6 + d];
        const float ov = fmaxf(s, 0.f);
        ctx[(size_t)bid * 192 + t] = ov;          // contiguous
        sE[t] = ov;                               // sE[pos*6+d]
    }
    __syncthreads();

    // output projection + logits partials (speculative when beta != 0)
    {
        const int ps = t & 31;
        for (int o = t >> 5; o < NC; o += 8) {
            float s = 0.f;
            #pragma unroll
            for (int d = 0; d < NI; ++d) s += Wo[o * NI + d] * sE[ps * NI + d];
            out[((size_t)(b * NC + o)) * N_POS + n0 + ps] = s + bo[o];
            #pragma unroll
            for (int off = 16; off > 0; off >>= 1) s += __shfl_down(s, off, 32);
            if (ps == 0) partial[o * 256 + bid] = s;
        }
    }

    // attention inputs, only when beta != 0
    if (*beta != 0.f && t < 32) {
        const int p = bid * 32 + t;
        const int n = n0 + t;
        float e[NI], cv[NI];
        #pragma unroll
        for (int d = 0; d < NI; ++d) e[d] = sE[t * NI + d];
        #pragma unroll
        for (int d = 0; d < NI; ++d)
            cv[d] = cam[((size_t)(b * NI + d)) * N_POS + n];
        #pragma unroll
        for (int o = 0; o < NI; ++o) {
            float s1 = bq[o], s2 = bk[o], s3 = bv[o], s4 = bcq[o], s5 = bck[o];
            #pragma unroll
            for (int d = 0; d < NI; ++d) {
                s1 += Wq[o * NI + d] * e[d];
                s2 += Wk[o * NI + d] * e[d];
                s3 += Wv[o * NI + d] * e[d];
                s4 += Wcq[o * NI + d] * cv[d];
                s5 += Wck[o * NI + d] * cv[d];
            }
            qb[(size_t)p * NI + o]  = s1;
            kb[(size_t)p * NI + o]  = s2;
            vb[(size_t)p * NI + o]  = s3;
            qdb[(size_t)p * NI + o] = s4;
            kdb[(size_t)p * NI + o] = s5;
        }
    }
}

// ---------------------------------------------------------------------------
// k_attn: attention (beta != 0 only) + last-block logits finalize (always).
// softmax((QD.KD)*(Q.K)/sqrt(6)) @ V; e = ctx + beta*enh; out = Wo@e + bo;
// overwrite logits partials. Grid: 128 blocks x 512 thr; 64 rows/block.
// Completion counter (zeroed by k_fused) elects the last block to finalize
// logits — deterministic: fixed-order sum independent of which block is last.
// ---------------------------------------------------------------------------
__global__ __launch_bounds__(512) void k_attn(
    const float* __restrict__ beta,
    const float* __restrict__ q,  const float* __restrict__ k,
    const float* __restrict__ v,  const float* __restrict__ qd,
    const float* __restrict__ kd, const float* __restrict__ ctx,
    const float* __restrict__ Wo, const float* __restrict__ bo,
    float* __restrict__ out, float* __restrict__ partial,
    int* __restrict__ counter, float* __restrict__ logits)
{
    __shared__ float sO[64][NC];
    __shared__ int lastFlag;

    const float bt = *beta;
    const int t = threadIdx.x;

    if (bt != 0.f) {
        const float inv_scale = 0.40824829046386296f; // 1/sqrt(6)
        const int r = t >> 3, lane8 = t & 7;
        const int p = blockIdx.x * 64 + r;
        const int b = p >> 12, n = p & 4095;
        const int base = b << 12;

        float qr[NI], qdr[NI];
        {
            const float* qp  = q  + (size_t)p * NI;
            const float* qdp = qd + (size_t)p * NI;
            #pragma unroll
            for (int d = 0; d < NI; ++d) { qr[d] = qp[d]; qdr[d] = qdp[d]; }
        }

        float mmax = -INFINITY, l = 0.f;
        float acc[NI] = {0.f, 0.f, 0.f, 0.f, 0.f, 0.f};

        for (int mi = 0; mi < 512; ++mi) {
            const int m = mi * 8 + lane8;
            const float* kp  = k  + (size_t)(base + m) * NI;
            const float* kdp = kd + (size_t)(base + m) * NI;
            const float* vp  = v  + (size_t)(base + m) * NI;
            float s1 = 0.f, s2 = 0.f;
            #pragma unroll
            for (int d = 0; d < NI; ++d) { s1 += qr[d] * kp[d]; s2 += qdr[d] * kdp[d]; }
            const float s = s1 * s2 * inv_scale;
            const float nm = fmaxf(mmax, s);
            const float corr = __expf(mmax - nm);
            const float e = __expf(s - nm);
            l = l * corr + e;
            #pragma unroll
            for (int d = 0; d < NI; ++d) acc[d] = acc[d] * corr + e * vp[d];
            mmax = nm;
        }

        #pragma unroll
        for (int off = 1; off < 8; off <<= 1) {
            const float om = __shfl_xor(mmax, off);
            const float ol = __shfl_xor(l, off);
            const float nm = fmaxf(mmax, om);
            const float c1 = __expf(mmax - nm);
            const float c2 = __expf(om - nm);
            l = l * c1 + ol * c2;
            #pragma unroll
            for (int d = 0; d < NI; ++d)
                acc[d] = acc[d] * c1 + __shfl_xor(acc[d], off) * c2;
            mmax = nm;
        }

        if (lane8 == 0) {
            const float invl = 1.f / l;
            float e[NI];
            const float* cp = ctx + (size_t)p * NI;
            #pragma unroll
            for (int d = 0; d < NI; ++d) e[d] = cp[d] + bt * acc[d] * invl;
            #pragma unroll
            for (int o = 0; o < NC; ++o) {
                float s = 0.f;
                #pragma unroll
                for (int d = 0; d < NI; ++d) s += Wo[o * NI + d] * e[d];
                out[((size_t)(b * NC + o)) * N_POS + n] = s + bo[o];
                sO[r][o] = s;
            }
        }
        __syncthreads();

        if (t < 2 * NC) {
            const int half = t / NC, o = t - half * NC;
            float s = 0.f;
            #pragma unroll
            for (int rr = 0; rr < 32; ++rr) s += sO[half * 32 + rr][o];
            partial[o * 256 + blockIdx.x * 2 + half] = s;
        }
    }

    // ---- completion counter + last-block logits finalize (both paths) ----
    __threadfence();
    __syncthreads();
    if (t == 0) lastFlag = (atomicAdd(counter, 1) == 127);
    __syncthreads();
    if (lastFlag) {
        __threadfence();
        if (t < 160) {
            const int combo = t >> 3, lane8 = t & 7;
            const int b = combo / NC, o = combo - b * NC;
            float s = 0.f;
            #pragma unroll
            for (int j = 0; j < 16; ++j)
                s += partial[o * 256 + b * 128 + lane8 * 16 + j];
            #pragma unroll
            for (int off = 4; off > 0; off >>= 1) s += __shfl_down(s, off, 8);
            if (lane8 == 0) logits[b * NC + o] = s * (1.f / 4096.f) + bo[o];
        }
    }
}

extern "C" void kernel_launch(void* const* d_in, const int* in_sizes, int n_in,
                              void* d_out, int out_size, void* d_ws, size_t ws_size,
                              hipStream_t stream)
{
    const float* feat = (const float*)d_in[0];
    const float* cam  = (const float*)d_in[1];
    const float* Wc  = (const float*)d_in[2];  const float* bc  = (const float*)d_in[3];
    const float* Wq  = (const float*)d_in[4];  const float* bq  = (const float*)d_in[5];
    const float* Wk  = (const float*)d_in[6];  const float* bk  = (const float*)d_in[7];
    const float* Wv  = (const float*)d_in[8];  const float* bv  = (const float*)d_in[9];
    const float* Wcq = (const float*)d_in[10]; const float* bcq = (const float*)d_in[11];
    const float* Wck = (const float*)d_in[12]; const float* bck = (const float*)d_in[13];
    const float* Wo  = (const float*)d_in[14]; const float* bo  = (const float*)d_in[15];
    const float* beta = (const float*)d_in[16];

    float* ws = (float*)d_ws;
    float* ctx     = ws;
    float* qb      = ws + 49152;
    float* kb      = ws + 98304;
    float* vb      = ws + 147456;
    float* qdb     = ws + 196608;
    float* kdb     = ws + 245760;
    float* partial = ws + 294912;          // [10][256]
    int*   counter = (int*)(ws + 297472);

    float* out    = (float*)d_out;         // [2][10][4096] maps
    float* logits = out + (size_t)B_SZ * NC * N_POS;

    k_fused<<<256, 256, 0, stream>>>(feat, cam, Wc, bc, Wq, bq, Wk, bk, Wv, bv,
                                     Wcq, bcq, Wck, bck, Wo, bo, beta,
                                     ctx, qb, kb, vb, qdb, kdb, partial, out, counter);
    k_attn<<<128, 512, 0, stream>>>(beta, qb, kb, vb, qdb, kdb, ctx, Wo, bo,
                                    out, partial, counter, logits);
}

// Round 5
// 11.224 us; speedup vs baseline: 2.5117x; 2.5117x over previous
//
#include <hip/hip_runtime.h>
#include <math.h>

#define NI 6
#define NC 10
#define C_IN 512
#define N_POS 4096
#define B_SZ 2

// ws layout (floats):
//   ctx     @ 0       [8192][6]
//   q       @ 49152   [8192][6]
//   k       @ 98304
//   v       @ 147456
//   qd      @ 196608
//   kd      @ 245760
//   partial @ 294912  [10][256]
//   counter @ 297472  (int)

// ---------------------------------------------------------------------------
// k_fused: context = relu(Wc@features+bc) -> out = Wo@context+bo + logits
// partials. ctx always written; Q/K/V/QD/KD iff beta != 0 (out/partials are
// then speculative; k_attn overwrites them). Block 0 zeroes the completion
// counter used only by the beta!=0 finalize in k_attn.
// Grid: 256 blocks x 256 thr. Block = 32 consecutive positions, 512 channels.
// Thread: quad q = t&7 (one float4 = 4 positions), ch = t>>3 (16 channels,
// c = cc*32+ch). Per channel a wave reads a full 128B line. (R3 structure —
// known 13.05 µs baseline.)
// ---------------------------------------------------------------------------
__global__ __launch_bounds__(256) void k_fused(
    const float* __restrict__ feat, const float* __restrict__ cam,
    const float* __restrict__ Wc,  const float* __restrict__ bc,
    const float* __restrict__ Wq,  const float* __restrict__ bq,
    const float* __restrict__ Wk,  const float* __restrict__ bk,
    const float* __restrict__ Wv,  const float* __restrict__ bv,
    const float* __restrict__ Wcq, const float* __restrict__ bcq,
    const float* __restrict__ Wck, const float* __restrict__ bck,
    const float* __restrict__ Wo,  const float* __restrict__ bo,
    const float* __restrict__ beta,
    float* __restrict__ ctx, float* __restrict__ qb, float* __restrict__ kb,
    float* __restrict__ vb, float* __restrict__ qdb, float* __restrict__ kdb,
    float* __restrict__ partial, float* __restrict__ out, int* __restrict__ counter)
{
    __shared__ float sW[C_IN * 8];        // [c][8] pad; d<6 valid
    __shared__ float sPart[32 * 8 * 25];  // [ch][q][24 + 1 pad] (25 coprime 32)
    __shared__ float sE[32 * NI];         // relu'd context, [pos][d]

    const int t   = threadIdx.x;
    const int bid = blockIdx.x;
    const int b   = bid >> 7;             // 128 blocks per batch
    const int n0  = (bid & 127) * 32;

    if (bid == 0 && t == 0) *counter = 0; // for beta!=0 finalize only

    // stage Wc ([6][512] row-major) transposed into sW[c*8+d]; coalesced reads
    #pragma unroll
    for (int i0 = 0; i0 < 12; ++i0) {
        const int i = t + i0 * 256;       // i = d*512 + c
        const int d = i >> 9, c = i & 511;
        sW[c * 8 + d] = Wc[i];
    }
    __syncthreads();

    const int q  = t & 7;                 // position quad: n0 + q*4 .. +3
    const int ch = t >> 3;                // 0..31
    const float* f = feat + (size_t)b * C_IN * N_POS + n0 + q * 4;

    float acc[24];                        // acc[po*6+d]
    #pragma unroll
    for (int i = 0; i < 24; ++i) acc[i] = 0.f;

    #pragma unroll
    for (int cc = 0; cc < 16; ++cc) {
        const int c = cc * 32 + ch;
        const float4 x  = *(const float4*)(f + (size_t)c * N_POS);
        const float4 w0 = *(const float4*)(&sW[c * 8]);
        const float2 w1 = *(const float2*)(&sW[c * 8 + 4]);
        acc[0]  += w0.x * x.x; acc[6]  += w0.x * x.y; acc[12] += w0.x * x.z; acc[18] += w0.x * x.w;
        acc[1]  += w0.y * x.x; acc[7]  += w0.y * x.y; acc[13] += w0.y * x.z; acc[19] += w0.y * x.w;
        acc[2]  += w0.z * x.x; acc[8]  += w0.z * x.y; acc[14] += w0.z * x.z; acc[20] += w0.z * x.w;
        acc[3]  += w0.w * x.x; acc[9]  += w0.w * x.y; acc[15] += w0.w * x.z; acc[21] += w0.w * x.w;
        acc[4]  += w1.x * x.x; acc[10] += w1.x * x.y; acc[16] += w1.x * x.z; acc[22] += w1.x * x.w;
        acc[5]  += w1.y * x.x; acc[11] += w1.y * x.y; acc[17] += w1.y * x.z; acc[23] += w1.y * x.w;
    }

    {
        float* sp = &sPart[(ch * 8 + q) * 25];
        #pragma unroll
        for (int j = 0; j < 24; ++j) sp[j] = acc[j];
    }
    __syncthreads();

    // reduce over the 32 channel-chunks: 192 threads, one (pos,d) each
    if (t < 192) {
        const int pos = t / 6, d = t - pos * 6;   // t == pos*6+d
        const int qq = pos >> 2, po = pos & 3;
        float s = bc[d];
        #pragma unroll
        for (int c2 = 0; c2 < 32; ++c2)
            s += sPart[(c2 * 8 + qq) * 25 + po * 6 + d];
        const float ov = fmaxf(s, 0.f);
        ctx[(size_t)bid * 192 + t] = ov;          // contiguous
        sE[t] = ov;                               // sE[pos*6+d]
    }
    __syncthreads();

    // output projection + logits partials (speculative when beta != 0)
    {
        const int ps = t & 31;
        for (int o = t >> 5; o < NC; o += 8) {
            float s = 0.f;
            #pragma unroll
            for (int d = 0; d < NI; ++d) s += Wo[o * NI + d] * sE[ps * NI + d];
            out[((size_t)(b * NC + o)) * N_POS + n0 + ps] = s + bo[o];
            #pragma unroll
            for (int off = 16; off > 0; off >>= 1) s += __shfl_down(s, off, 32);
            if (ps == 0) partial[o * 256 + bid] = s;
        }
    }

    // attention inputs, only when beta != 0
    if (*beta != 0.f && t < 32) {
        const int p = bid * 32 + t;
        const int n = n0 + t;
        float e[NI], cv[NI];
        #pragma unroll
        for (int d = 0; d < NI; ++d) e[d] = sE[t * NI + d];
        #pragma unroll
        for (int d = 0; d < NI; ++d)
            cv[d] = cam[((size_t)(b * NI + d)) * N_POS + n];
        #pragma unroll
        for (int o = 0; o < NI; ++o) {
            float s1 = bq[o], s2 = bk[o], s3 = bv[o], s4 = bcq[o], s5 = bck[o];
            #pragma unroll
            for (int d = 0; d < NI; ++d) {
                s1 += Wq[o * NI + d] * e[d];
                s2 += Wk[o * NI + d] * e[d];
                s3 += Wv[o * NI + d] * e[d];
                s4 += Wcq[o * NI + d] * cv[d];
                s5 += Wck[o * NI + d] * cv[d];
            }
            qb[(size_t)p * NI + o]  = s1;
            kb[(size_t)p * NI + o]  = s2;
            vb[(size_t)p * NI + o]  = s3;
            qdb[(size_t)p * NI + o] = s4;
            kdb[(size_t)p * NI + o] = s5;
        }
    }
}

// ---------------------------------------------------------------------------
// k_attn:
//  beta == 0 (hot path): blocks 1..127 exit; block 0 finalizes logits from
//    k_fused's partials. Cross-kernel visibility is guaranteed by stream
//    ordering — NO fences, NO atomics (R4's __threadfence L2 writebacks were
//    the +15 µs regression).
//  beta != 0 (cold path): full attention + out/partial overwrite, then
//    counter-elected last block finalizes logits (fences acceptable there).
// Grid: 128 blocks x 512 thr; 64 rows/block.
// ---------------------------------------------------------------------------
__global__ __launch_bounds__(512) void k_attn(
    const float* __restrict__ beta,
    const float* __restrict__ q,  const float* __restrict__ k,
    const float* __restrict__ v,  const float* __restrict__ qd,
    const float* __restrict__ kd, const float* __restrict__ ctx,
    const float* __restrict__ Wo, const float* __restrict__ bo,
    float* __restrict__ out, float* __restrict__ partial,
    int* __restrict__ counter, float* __restrict__ logits)
{
    const float bt = *beta;
    const int t = threadIdx.x;

    if (bt == 0.f) {
        // hot path: only block 0 does work — sum partials -> logits
        if (blockIdx.x == 0 && t < 160) {
            const int combo = t >> 3, lane8 = t & 7;
            const int b = combo / NC, o = combo - b * NC;
            float s = 0.f;
            #pragma unroll
            for (int j = 0; j < 16; ++j)
                s += partial[o * 256 + b * 128 + lane8 * 16 + j];
            #pragma unroll
            for (int off = 4; off > 0; off >>= 1) s += __shfl_down(s, off, 8);
            if (lane8 == 0) logits[b * NC + o] = s * (1.f / 4096.f) + bo[o];
        }
        return;
    }

    // ---------------- cold path: beta != 0 ----------------
    __shared__ float sO[64][NC];
    __shared__ int lastFlag;

    {
        const float inv_scale = 0.40824829046386296f; // 1/sqrt(6)
        const int r = t >> 3, lane8 = t & 7;
        const int p = blockIdx.x * 64 + r;
        const int b = p >> 12, n = p & 4095;
        const int base = b << 12;

        float qr[NI], qdr[NI];
        {
            const float* qp  = q  + (size_t)p * NI;
            const float* qdp = qd + (size_t)p * NI;
            #pragma unroll
            for (int d = 0; d < NI; ++d) { qr[d] = qp[d]; qdr[d] = qdp[d]; }
        }

        float mmax = -INFINITY, l = 0.f;
        float acc[NI] = {0.f, 0.f, 0.f, 0.f, 0.f, 0.f};

        for (int mi = 0; mi < 512; ++mi) {
            const int m = mi * 8 + lane8;
            const float* kp  = k  + (size_t)(base + m) * NI;
            const float* kdp = kd + (size_t)(base + m) * NI;
            const float* vp  = v  + (size_t)(base + m) * NI;
            float s1 = 0.f, s2 = 0.f;
            #pragma unroll
            for (int d = 0; d < NI; ++d) { s1 += qr[d] * kp[d]; s2 += qdr[d] * kdp[d]; }
            const float s = s1 * s2 * inv_scale;
            const float nm = fmaxf(mmax, s);
            const float corr = __expf(mmax - nm);
            const float e = __expf(s - nm);
            l = l * corr + e;
            #pragma unroll
            for (int d = 0; d < NI; ++d) acc[d] = acc[d] * corr + e * vp[d];
            mmax = nm;
        }

        #pragma unroll
        for (int off = 1; off < 8; off <<= 1) {
            const float om = __shfl_xor(mmax, off);
            const float ol = __shfl_xor(l, off);
            const float nm = fmaxf(mmax, om);
            const float c1 = __expf(mmax - nm);
            const float c2 = __expf(om - nm);
            l = l * c1 + ol * c2;
            #pragma unroll
            for (int d = 0; d < NI; ++d)
                acc[d] = acc[d] * c1 + __shfl_xor(acc[d], off) * c2;
            mmax = nm;
        }

        if (lane8 == 0) {
            const float invl = 1.f / l;
            float e[NI];
            const float* cp = ctx + (size_t)p * NI;
            #pragma unroll
            for (int d = 0; d < NI; ++d) e[d] = cp[d] + bt * acc[d] * invl;
            #pragma unroll
            for (int o = 0; o < NC; ++o) {
                float s = 0.f;
                #pragma unroll
                for (int d = 0; d < NI; ++d) s += Wo[o * NI + d] * e[d];
                out[((size_t)(b * NC + o)) * N_POS + n] = s + bo[o];
                sO[r][o] = s;
            }
        }
        __syncthreads();

        if (t < 2 * NC) {
            const int half = t / NC, o = t - half * NC;
            float s = 0.f;
            #pragma unroll
            for (int rr = 0; rr < 32; ++rr) s += sO[half * 32 + rr][o];
            partial[o * 256 + blockIdx.x * 2 + half] = s;
        }
    }

    // last-block logits finalize (cold path only — fences off the hot path)
    __threadfence();
    __syncthreads();
    if (t == 0) lastFlag = (atomicAdd(counter, 1) == 127);
    __syncthreads();
    if (lastFlag) {
        __threadfence();
        if (t < 160) {
            const int combo = t >> 3, lane8 = t & 7;
            const int b = combo / NC, o = combo - b * NC;
            float s = 0.f;
            #pragma unroll
            for (int j = 0; j < 16; ++j)
                s += partial[o * 256 + b * 128 + lane8 * 16 + j];
            #pragma unroll
            for (int off = 4; off > 0; off >>= 1) s += __shfl_down(s, off, 8);
            if (lane8 == 0) logits[b * NC + o] = s * (1.f / 4096.f) + bo[o];
        }
    }
}

extern "C" void kernel_launch(void* const* d_in, const int* in_sizes, int n_in,
                              void* d_out, int out_size, void* d_ws, size_t ws_size,
                              hipStream_t stream)
{
    const float* feat = (const float*)d_in[0];
    const float* cam  = (const float*)d_in[1];
    const float* Wc  = (const float*)d_in[2];  const float* bc  = (const float*)d_in[3];
    const float* Wq  = (const float*)d_in[4];  const float* bq  = (const float*)d_in[5];
    const float* Wk  = (const float*)d_in[6];  const float* bk  = (const float*)d_in[7];
    const float* Wv  = (const float*)d_in[8];  const float* bv  = (const float*)d_in[9];
    const float* Wcq = (const float*)d_in[10]; const float* bcq = (const float*)d_in[11];
    const float* Wck = (const float*)d_in[12]; const float* bck = (const float*)d_in[13];
    const float* Wo  = (const float*)d_in[14]; const float* bo  = (const float*)d_in[15];
    const float* beta = (const float*)d_in[16];

    float* ws = (float*)d_ws;
    float* ctx     = ws;
    float* qb      = ws + 49152;
    float* kb      = ws + 98304;
    float* vb      = ws + 147456;
    float* qdb     = ws + 196608;
    float* kdb     = ws + 245760;
    float* partial = ws + 294912;          // [10][256]
    int*   counter = (int*)(ws + 297472);

    float* out    = (float*)d_out;         // [2][10][4096] maps
    float* logits = out + (size_t)B_SZ * NC * N_POS;

    k_fused<<<256, 256, 0, stream>>>(feat, cam, Wc, bc, Wq, bq, Wk, bk, Wv, bv,
                                     Wcq, bcq, Wck, bck, Wo, bo, beta,
                                     ctx, qb, kb, vb, qdb, kdb, partial, out, counter);
    k_attn<<<128, 512, 0, stream>>>(beta, qb, kb, vb, qdb, kdb, ctx, Wo, bo,
                                    out, partial, counter, logits);
}